// Round 14
// baseline (655.362 us; speedup 1.0000x reference)
//
#include <hip/hip_runtime.h>
#include <hip/hip_bf16.h>
#include <math.h>
#include <stdint.h>

#define N_NODES   4096
#define HDIM      512
#define NUM_HEADS 8
#define HEAD_DIM  64
#define NUM_SETS  1365
#define KDIM      512
#define NBLK      512

typedef __attribute__((ext_vector_type(8))) short bf16x8;
typedef __attribute__((ext_vector_type(4))) float f32x4;

__device__ inline unsigned short f2bfu(float x) {
    __hip_bfloat16 h = __float2bfloat16(x);
    return __builtin_bit_cast(unsigned short, h);
}
__device__ inline float bfu2f(unsigned short u) {
    unsigned v = (unsigned)u << 16;
    return __builtin_bit_cast(float, v);
}

__device__ inline void gload_lds16(const void* g, void* l) {
    __builtin_amdgcn_global_load_lds(
        (const __attribute__((address_space(1))) unsigned int*)g,
        (__attribute__((address_space(3))) unsigned int*)l,
        16, 0, 0);
}

// ---- software grid barrier: LOAD-spin (R13's RMW-spin serialized at ~63us/barrier) ----
// All 512 blocks co-resident by construction (64KB LDS + <=128 VGPR -> 2 blocks/CU).
__device__ __forceinline__ void gsync(unsigned* cnt) {
    __syncthreads();                                   // block quiesce
    if (threadIdx.x == 0) {
        __threadfence();                               // release: publish my stores
        __hip_atomic_fetch_add(cnt, 1u, __ATOMIC_RELEASE, __HIP_MEMORY_SCOPE_AGENT);
        while (__hip_atomic_load(cnt, __ATOMIC_ACQUIRE, __HIP_MEMORY_SCOPE_AGENT) < NBLK)
            __builtin_amdgcn_s_sleep(2);               // concurrent reads: no ownership churn
        __threadfence();                               // acquire: invalidate stale lines
    }
    __syncthreads();
}

// ---------------- stage 0: prep (wconv + emb->bf16 + seg bounds), 512 thr ----------------
__device__ __forceinline__ void prep_body(char* smem,
        const float* W0, const float* W1, const float* W2, const float* W3,
        const float* W4, const float* W5, const float* W6, const float* W7,
        const float* W8, __hip_bfloat16* wt,
        const float* emb, __hip_bfloat16* embb,
        const int* batch, int* seg_s, int* seg_e) {
    auto tf = reinterpret_cast<float(*)[32][36]>(smem);   // [2][32][36]
    const int sub  = threadIdx.x >> 8;                    // two 256-thr sub-blocks
    const int t256 = threadIdx.x & 255;
    #pragma unroll 1
    for (int it = 0; it < 3; ++it) {                      // 2304 tiles, 1024/iter
        const int item = it * 1024 + (int)blockIdx.x * 2 + sub;
        const bool v = item < 2304;
        const float* W = nullptr; __hip_bfloat16* Wt = nullptr;
        int bn = 0, bk = 0;
        if (v) {
            const int z = item >> 8, tb = item & 255;
            W = z==0?W0:z==1?W1:z==2?W2:z==3?W3:z==4?W4:z==5?W5:z==6?W6:z==7?W7:W8;
            Wt = wt + (size_t)z * (512 * 512);
            bn = (tb & 15) * 32; bk = (tb >> 4) * 32;
            const int nx = t256 & 7, ky = t256 >> 3;
            *(float4*)&tf[sub][ky][nx * 4] =
                *(const float4*)&W[(size_t)(bk + ky) * 512 + bn + nx * 4];
        }
        __syncthreads();
        if (v) {
            const int r2 = t256 >> 3, ck = t256 & 7;
            uint2 p;
            p.x = (unsigned)f2bfu(tf[sub][ck*4+0][r2]) | ((unsigned)f2bfu(tf[sub][ck*4+1][r2]) << 16);
            p.y = (unsigned)f2bfu(tf[sub][ck*4+2][r2]) | ((unsigned)f2bfu(tf[sub][ck*4+3][r2]) << 16);
            *(uint2*)&Wt[(size_t)(bn + r2) * 512 + bk + ck * 4] = p;
        }
        __syncthreads();
    }
    // emb fp32 -> bf16: 524288 float4, exactly 2 iters
    const int base = (int)blockIdx.x * 512 + (int)threadIdx.x;
    #pragma unroll
    for (int it = 0; it < 2; ++it) {
        const int i = it * (NBLK * 512) + base;
        float4 vv = ((const float4*)emb)[i];
        uint2 p;
        p.x = (unsigned)f2bfu(vv.x) | ((unsigned)f2bfu(vv.y) << 16);
        p.y = (unsigned)f2bfu(vv.z) | ((unsigned)f2bfu(vv.w) << 16);
        ((uint2*)embb)[i] = p;
    }
    // segment bounds (batch sorted): first 4096 threads
    if (base < N_NODES) {
        const int bi = batch[base];
        if (base == 0 || batch[base - 1] != bi) {
            int e = base + 1;
            while (e < N_NODES && batch[e] == bi) ++e;
            for (int j = base; j < e; ++j) { seg_s[j] = base; seg_e[j] = e; }
        }
    }
}

// ---------------- gemm128 stage: 128x128, BK=64, 8 waves, R12 schedule ----------------
template<int MODE>
__device__ __forceinline__ void gemm_body(char* smem,
        const __hip_bfloat16* A,
        const __hip_bfloat16* Wt0, const __hip_bfloat16* Wt1,
        const __hip_bfloat16* Wt2, const __hip_bfloat16* Wt3,
        const float* bias0, const float* bias1, const float* bias2, const float* bias3,
        __hip_bfloat16* statB, __hip_bfloat16* outB) {
    constexpr int NITEMS = (MODE == 0) ? 512 : 384;
    const int item = (int)blockIdx.x;
    if (item >= NITEMS) return;                       // whole block skips (no barriers inside)
    auto Al = reinterpret_cast<short(*)[128][64]>(smem);           // [2][128][64]
    auto Bl = reinterpret_cast<short(*)[128][64]>(smem + 32768);

    const int wid = threadIdx.x >> 6, lane = threadIdx.x & 63;
    const int brow = (item & 31) * 128;               // xcd = item%8 = bx%8: A-panel locality
    const int yy = item >> 5;
    const int wsel = yy >> 2;
    const int bcol = (yy & 3) * 128;
    const __hip_bfloat16* Wt = (wsel == 0) ? Wt0 : (wsel == 1) ? Wt1 : (wsel == 2) ? Wt2 : Wt3;
    const float* bias        = (wsel == 0) ? bias0 : (wsel == 1) ? bias1 : (wsel == 2) ? bias2 : bias3;

    const int swzc = (lane & 7) ^ ((lane >> 3) & 7);
    const __hip_bfloat16* aSrc = A  + (size_t)(brow + wid * 16 + (lane >> 3)) * KDIM + swzc * 8;
    const __hip_bfloat16* bSrc = Wt + (size_t)(bcol + wid * 16 + (lane >> 3)) * KDIM + swzc * 8;

    const int fr = lane & 15, fq = lane >> 4;
    const int rx = fr & 7;
    const int wm = (wid >> 1) * 32;
    const int wn = (wid & 1) * 64;

    auto STAGE = [&](int buf, int t) {
        const int k0 = t * 64;
        gload_lds16(aSrc + k0, &Al[buf][wid * 16][0]);
        gload_lds16(aSrc + k0 + (size_t)8 * KDIM, &Al[buf][wid * 16 + 8][0]);
        gload_lds16(bSrc + k0, &Bl[buf][wid * 16][0]);
        gload_lds16(bSrc + k0 + (size_t)8 * KDIM, &Bl[buf][wid * 16 + 8][0]);
    };

    STAGE(0, 0);
    STAGE(1, 1);

    const int ch0 = ((0 + fq) ^ rx) * 8;
    const int ch1 = ((4 + fq) ^ rx) * 8;

    f32x4 acc[2][4] = {};
    #pragma unroll
    for (int t = 0; t < 8; ++t) {
        const int cur = t & 1;
        if (t < 7) asm volatile("s_waitcnt vmcnt(4)" ::: "memory");
        else       asm volatile("s_waitcnt vmcnt(0)" ::: "memory");
        __builtin_amdgcn_s_barrier();
        __builtin_amdgcn_sched_barrier(0);
        bf16x8 a0[2], a1[2], b0[4], b1[4];
        #pragma unroll
        for (int mi = 0; mi < 2; ++mi) {
            a0[mi] = *(const bf16x8*)&Al[cur][wm + mi * 16 + fr][ch0];
            a1[mi] = *(const bf16x8*)&Al[cur][wm + mi * 16 + fr][ch1];
        }
        #pragma unroll
        for (int ni = 0; ni < 4; ++ni) {
            b0[ni] = *(const bf16x8*)&Bl[cur][wn + ni * 16 + fr][ch0];
            b1[ni] = *(const bf16x8*)&Bl[cur][wn + ni * 16 + fr][ch1];
        }
        asm volatile("s_waitcnt lgkmcnt(0)" ::: "memory");
        __builtin_amdgcn_sched_barrier(0);
        __builtin_amdgcn_s_barrier();
        if (t + 2 < 8) STAGE(cur, t + 2);
        __builtin_amdgcn_sched_barrier(0);
        __builtin_amdgcn_s_setprio(1);
        #pragma unroll
        for (int mi = 0; mi < 2; ++mi)
            #pragma unroll
            for (int ni = 0; ni < 4; ++ni) {
                acc[mi][ni] = __builtin_amdgcn_mfma_f32_16x16x32_bf16(a0[mi], b0[ni], acc[mi][ni], 0, 0, 0);
                acc[mi][ni] = __builtin_amdgcn_mfma_f32_16x16x32_bf16(a1[mi], b1[ni], acc[mi][ni], 0, 0, 0);
            }
        __builtin_amdgcn_s_setprio(0);
    }

    float bv[4];
    #pragma unroll
    for (int ni = 0; ni < 4; ++ni) bv[ni] = bias[bcol + wn + ni * 16 + fr];

    #pragma unroll
    for (int mi = 0; mi < 2; ++mi) {
        #pragma unroll
        for (int ni = 0; ni < 4; ++ni) {
            const int c = bcol + wn + ni * 16 + fr;
            #pragma unroll
            for (int r = 0; r < 4; ++r) {
                const int row = brow + wm + mi * 16 + fq * 4 + r;
                const float v = acc[mi][ni][r] + bv[ni];
                if (MODE == 0) {
                    if (wsel == 0) statB[(size_t)row * 512 + c] = __float2bfloat16(fmaxf(v, 0.f));
                    else           outB[(size_t)row * 1536 + (wsel - 1) * 512 + c] = __float2bfloat16(v);
                } else {
                    outB[(size_t)row * 1536 + wsel * 512 + c] = __float2bfloat16(v);
                }
            }
        }
    }
}

// ---------------- oproj stage: 64x64 tiles, waves 0-3 active, waves 4-7 barrier-only ------
__device__ __forceinline__ void oproj_body(char* smem,
        const __hip_bfloat16* A, const __hip_bfloat16* Wt, const float* bias,
        const __hip_bfloat16* X, const float* betaP, __hip_bfloat16* outB) {
    auto Al = reinterpret_cast<short(*)[64][64]>(smem);            // [2][64][64]
    auto Bl = reinterpret_cast<short(*)[64][64]>(smem + 16384);

    const int wid = threadIdx.x >> 6, lane = threadIdx.x & 63;
    const bool act = wid < 4;
    const int item = (int)blockIdx.x;
    const int brow = (item & 63) * 64;                // xcd = item%8 = bx%8: A-panel locality
    const int bcol = (item >> 6) * 64;

    const int swzc = (lane & 7) ^ ((lane >> 3) & 7);
    const __hip_bfloat16* aSrc = A  + (size_t)(brow + wid * 16 + (lane >> 3)) * KDIM + swzc * 8;
    const __hip_bfloat16* bSrc = Wt + (size_t)(bcol + wid * 16 + (lane >> 3)) * KDIM + swzc * 8;

    const int fr = lane & 15, fq = lane >> 4;
    const int rx = fr & 7;
    const int wm = (wid >> 1) * 32, wn = (wid & 1) * 32;

    auto STAGE = [&](int buf, int t) {
        const int k0 = t * 64;
        gload_lds16(aSrc + k0, &Al[buf][wid * 16][0]);
        gload_lds16(aSrc + k0 + (size_t)8 * KDIM, &Al[buf][wid * 16 + 8][0]);
        gload_lds16(bSrc + k0, &Bl[buf][wid * 16][0]);
        gload_lds16(bSrc + k0 + (size_t)8 * KDIM, &Bl[buf][wid * 16 + 8][0]);
    };

    if (act) { STAGE(0, 0); STAGE(1, 1); }

    const int ch0 = ((0 + fq) ^ rx) * 8;
    const int ch1 = ((4 + fq) ^ rx) * 8;

    f32x4 acc[2][2] = {};
    #pragma unroll
    for (int t = 0; t < 8; ++t) {
        const int cur = t & 1;
        if (t < 7) asm volatile("s_waitcnt vmcnt(4)" ::: "memory");   // no-op for idle waves
        else       asm volatile("s_waitcnt vmcnt(0)" ::: "memory");
        __builtin_amdgcn_s_barrier();
        __builtin_amdgcn_sched_barrier(0);
        bf16x8 a0[2], a1[2], b0[2], b1[2];
        if (act) {
            #pragma unroll
            for (int mi = 0; mi < 2; ++mi) {
                a0[mi] = *(const bf16x8*)&Al[cur][wm + mi * 16 + fr][ch0];
                a1[mi] = *(const bf16x8*)&Al[cur][wm + mi * 16 + fr][ch1];
            }
            #pragma unroll
            for (int ni = 0; ni < 2; ++ni) {
                b0[ni] = *(const bf16x8*)&Bl[cur][wn + ni * 16 + fr][ch0];
                b1[ni] = *(const bf16x8*)&Bl[cur][wn + ni * 16 + fr][ch1];
            }
        }
        asm volatile("s_waitcnt lgkmcnt(0)" ::: "memory");
        __builtin_amdgcn_sched_barrier(0);
        __builtin_amdgcn_s_barrier();
        if (act && t + 2 < 8) STAGE(cur, t + 2);
        __builtin_amdgcn_sched_barrier(0);
        if (act) {
            __builtin_amdgcn_s_setprio(1);
            #pragma unroll
            for (int mi = 0; mi < 2; ++mi)
                #pragma unroll
                for (int ni = 0; ni < 2; ++ni) {
                    acc[mi][ni] = __builtin_amdgcn_mfma_f32_16x16x32_bf16(a0[mi], b0[ni], acc[mi][ni], 0, 0, 0);
                    acc[mi][ni] = __builtin_amdgcn_mfma_f32_16x16x32_bf16(a1[mi], b1[ni], acc[mi][ni], 0, 0, 0);
                }
            __builtin_amdgcn_s_setprio(0);
        }
    }

    if (act) {
        float bv[2];
        #pragma unroll
        for (int ni = 0; ni < 2; ++ni) bv[ni] = bias[bcol + wn + ni * 16 + fr];
        const float beta = betaP[0];
        #pragma unroll
        for (int mi = 0; mi < 2; ++mi) {
            #pragma unroll
            for (int ni = 0; ni < 2; ++ni) {
                const int c = bcol + wn + ni * 16 + fr;
                #pragma unroll
                for (int r = 0; r < 4; ++r) {
                    const int row = brow + wm + mi * 16 + fq * 4 + r;
                    const float xv = __bfloat162float(X[(size_t)row * 512 + c]);
                    outB[(size_t)row * 512 + c] =
                        __float2bfloat16(beta * (acc[mi][ni][r] + bv[ni]) + xv);
                }
            }
        }
    }
}

// ---------------- attn stage: one wave per node (8 waves/block x 512 blocks = 4096) -------
__device__ __forceinline__ void attn_body(
        const __hip_bfloat16* qkv, const int* seg_s, const int* seg_e,
        __hip_bfloat16* ab) {
    const int wid  = threadIdx.x >> 6;
    const int node = (int)blockIdx.x * 8 + wid;
    const int lane = threadIdx.x & 63;
    const int c8   = lane * 8;

    bf16x8 q8 = *(const bf16x8*)&qkv[(size_t)node * 1536 + c8];
    float qf[8];
    #pragma unroll
    for (int j = 0; j < 8; ++j) qf[j] = bfu2f((unsigned short)q8[j]);

    const int s = seg_s[node], e = seg_e[node];

    float M = -INFINITY, S = 0.f;
    float o[8] = {};
    for (int m = s; m < e; ++m) {
        if (m == node) continue;
        bf16x8 k8 = *(const bf16x8*)&qkv[(size_t)m * 1536 + 512 + c8];
        float p = 0.f;
        #pragma unroll
        for (int j = 0; j < 8; ++j) p = fmaf(qf[j], bfu2f((unsigned short)k8[j]), p);
        p += __shfl_xor(p, 1, 64);
        p += __shfl_xor(p, 2, 64);
        p += __shfl_xor(p, 4, 64);
        const float sc = p * 0.125f;
        const float newM = fmaxf(M, sc);
        const float scale = __expf(M - newM);
        const float w = __expf(sc - newM);
        S = S * scale + w;
        bf16x8 v8 = *(const bf16x8*)&qkv[(size_t)m * 1536 + 1024 + c8];
        #pragma unroll
        for (int j = 0; j < 8; ++j) o[j] = fmaf(w, bfu2f((unsigned short)v8[j]), o[j] * scale);
        M = newM;
    }
    const float inv = (S > 0.f) ? (1.f / S) : 0.f;
    bf16x8 r;
    #pragma unroll
    for (int j = 0; j < 8; ++j) r[j] = (short)f2bfu(o[j] * inv);
    *(bf16x8*)&ab[(size_t)node * 512 + c8] = r;
}

// ---------------- mse stage: one set per block per pass, 512 thr = 512 cols ----------------
__device__ __forceinline__ void mse_body(
        const unsigned short* dyn, const unsigned short* stat,
        const int* batch, float* out) {
    const int d = threadIdx.x;
    for (int s = (int)blockIdx.x; s < NUM_SETS; s += NBLK) {
        int lo = 0, hi = N_NODES;
        while (lo < hi) { int m = (lo + hi) >> 1; if (batch[m] < s) lo = m + 1; else hi = m; }
        const int a = lo;
        hi = N_NODES;
        while (lo < hi) { int m = (lo + hi) >> 1; if (batch[m] <= s) lo = m + 1; else hi = m; }
        const int b = lo;
        float acc = 0.f;
        for (int i = a; i < b; ++i) {
            const float df = bfu2f(dyn[(size_t)i * 512 + d]) - bfu2f(stat[(size_t)i * 512 + d]);
            acc += df * df;
        }
        out[(size_t)s * 512 + d] = acc / fmaxf((float)(b - a), 1.f);
    }
}

// ---------------- the mega-kernel: whole pipeline, 7 software grid barriers ----------------
__global__ __launch_bounds__(512, 4) void mega_kernel(
        const float* emb, const int* batch,
        const float* W0, const float* W1, const float* W2, const float* W3,
        const float* W4, const float* W5, const float* W6, const float* W7, const float* W8,
        const float* bs_, const float* bq1, const float* bk1, const float* bv1,
        const float* bo1, const float* beta1,
        const float* bq2, const float* bk2, const float* bv2,
        const float* bo2, const float* beta2,
        __hip_bfloat16* wt, __hip_bfloat16* embb, __hip_bfloat16* statB,
        __hip_bfloat16* qkv, __hip_bfloat16* ab, __hip_bfloat16* dynb,
        __hip_bfloat16* dyn2b, int* seg_s, int* seg_e,
        unsigned* gcnt, float* out) {
    __shared__ __align__(16) char smem[65536];
    const size_t WSZ = 512 * 512;
    const __hip_bfloat16* wtS  = wt + 0 * WSZ;
    const __hip_bfloat16* wtQ1 = wt + 1 * WSZ;
    const __hip_bfloat16* wtK1 = wt + 2 * WSZ;
    const __hip_bfloat16* wtV1 = wt + 3 * WSZ;
    const __hip_bfloat16* wtO1 = wt + 4 * WSZ;
    const __hip_bfloat16* wtQ2 = wt + 5 * WSZ;
    const __hip_bfloat16* wtK2 = wt + 6 * WSZ;
    const __hip_bfloat16* wtV2 = wt + 7 * WSZ;
    const __hip_bfloat16* wtO2 = wt + 8 * WSZ;

    prep_body(smem, W0, W1, W2, W3, W4, W5, W6, W7, W8, wt, emb, embb, batch, seg_s, seg_e);
    gsync(&gcnt[0]);
    gemm_body<0>(smem, embb, wtS, wtQ1, wtK1, wtV1, bs_, bq1, bk1, bv1, statB, qkv);
    gsync(&gcnt[1]);
    attn_body(qkv, seg_s, seg_e, ab);
    gsync(&gcnt[2]);
    oproj_body(smem, ab, wtO1, bo1, embb, beta1, dynb);
    gsync(&gcnt[3]);
    gemm_body<1>(smem, dynb, wtQ2, wtK2, wtV2, wtV2, bq2, bk2, bv2, bv2, nullptr, qkv);
    gsync(&gcnt[4]);
    attn_body(qkv, seg_s, seg_e, ab);
    gsync(&gcnt[5]);
    oproj_body(smem, ab, wtO2, bo2, dynb, beta2, dyn2b);
    gsync(&gcnt[6]);
    mse_body((const unsigned short*)dyn2b, (const unsigned short*)statB, batch, out);
}

extern "C" void kernel_launch(void* const* d_in, const int* in_sizes, int n_in,
                              void* d_out, int out_size, void* d_ws, size_t ws_size,
                              hipStream_t stream) {
    const float* emb   = (const float*)d_in[0];
    const int*   batch = (const int*)  d_in[1];
    const float* Ws_   = (const float*)d_in[2];
    const float* bs_   = (const float*)d_in[3];
    const float* Wq1 = (const float*)d_in[4];  const float* bq1 = (const float*)d_in[5];
    const float* Wk1 = (const float*)d_in[6];  const float* bk1 = (const float*)d_in[7];
    const float* Wv1 = (const float*)d_in[8];  const float* bv1 = (const float*)d_in[9];
    const float* Wo1 = (const float*)d_in[10]; const float* bo1 = (const float*)d_in[11];
    const float* beta1 = (const float*)d_in[12];
    const float* Wq2 = (const float*)d_in[13]; const float* bq2 = (const float*)d_in[14];
    const float* Wk2 = (const float*)d_in[15]; const float* bk2 = (const float*)d_in[16];
    const float* Wv2 = (const float*)d_in[17]; const float* bv2 = (const float*)d_in[18];
    const float* Wo2 = (const float*)d_in[19]; const float* bo2 = (const float*)d_in[20];
    const float* beta2 = (const float*)d_in[21];

    char* w = (char*)d_ws;
    const size_t MB = 1024 * 1024;
    __hip_bfloat16* statB  = (__hip_bfloat16*)(w + 0 * MB);   // 4 MiB
    __hip_bfloat16* qkv    = (__hip_bfloat16*)(w + 4 * MB);   // 12 MiB
    __hip_bfloat16* embb   = (__hip_bfloat16*)(w + 16 * MB);  // 4 MiB
    __hip_bfloat16* ab     = (__hip_bfloat16*)(w + 20 * MB);  // 4 MiB
    __hip_bfloat16* dynb   = (__hip_bfloat16*)(w + 24 * MB);  // 4 MiB
    __hip_bfloat16* dyn2b  = (__hip_bfloat16*)(w + 28 * MB);  // 4 MiB
    __hip_bfloat16* wt     = (__hip_bfloat16*)(w + 32 * MB);  // 4.5 MiB
    int* seg_s = (int*)(w + 37 * MB);
    int* seg_e = seg_s + N_NODES;
    unsigned* gcnt = (unsigned*)(w + 37 * MB + 64 * 1024);

    // reset barrier counters each launch (graph-replay deterministic)
    hipMemsetAsync(gcnt, 0, 7 * sizeof(unsigned), stream);

    mega_kernel<<<NBLK, 512, 0, stream>>>(
        emb, batch, Ws_, Wq1, Wk1, Wv1, Wo1, Wq2, Wk2, Wv2, Wo2,
        bs_, bq1, bk1, bv1, bo1, beta1, bq2, bk2, bv2, bo2, beta2,
        wt, embb, statB, qkv, ab, dynb, dyn2b, seg_s, seg_e,
        gcnt, (float*)d_out);
}

// Round 15
// 72.710 us; speedup vs baseline: 9.0134x; 9.0134x over previous
//
#include <hip/hip_runtime.h>
#include <hip/hip_bf16.h>
#include <math.h>
#include <stdint.h>

#define N_NODES   4096
#define HDIM      512
#define NUM_HEADS 8
#define HEAD_DIM  64
#define NUM_SETS  1365
#define KDIM      512

typedef __attribute__((ext_vector_type(8))) short bf16x8;
typedef __attribute__((ext_vector_type(4))) float f32x4;

__device__ inline unsigned short f2bfu(float x) {
    __hip_bfloat16 h = __float2bfloat16(x);
    return __builtin_bit_cast(unsigned short, h);
}
__device__ inline float bfu2f(unsigned short u) {
    unsigned v = (unsigned)u << 16;
    return __builtin_bit_cast(float, v);
}

__device__ inline void gload_lds16(const void* g, void* l) {
    __builtin_amdgcn_global_load_lds(
        (const __attribute__((address_space(1))) unsigned int*)g,
        (__attribute__((address_space(3))) unsigned int*)l,
        16, 0, 0);
}

// ---------------- fused prelude: wconv (blocks 0..2303) | f2bf4 (..4351) | seg_bounds (..4367)
__global__ __launch_bounds__(256) void prep_kernel(
        const float* W0, const float* W1, const float* W2, const float* W3,
        const float* W4, const float* W5, const float* W6, const float* W7,
        const float* W8, __hip_bfloat16* __restrict__ wt,
        const float* __restrict__ emb, __hip_bfloat16* __restrict__ embb,
        const int* __restrict__ batch,
        int* __restrict__ seg_s, int* __restrict__ seg_e) {
    const int bx = blockIdx.x;
    if (bx < 2304) {
        __shared__ float t[32][36];
        const int z = bx >> 8;
        const int tb = bx & 255;
        const float* W = z==0?W0:z==1?W1:z==2?W2:z==3?W3:z==4?W4:z==5?W5:z==6?W6:z==7?W7:W8;
        __hip_bfloat16* Wt = wt + (size_t)z * (512 * 512);
        const int bn = (tb & 15) * 32, bk = (tb >> 4) * 32;
        const int nx = threadIdx.x & 7, ky = threadIdx.x >> 3;
        *(float4*)&t[ky][nx * 4] = *(const float4*)&W[(size_t)(bk + ky) * 512 + bn + nx * 4];
        __syncthreads();
        const int r2 = threadIdx.x >> 3;
        const int ck = threadIdx.x & 7;
        uint2 p;
        p.x = (unsigned)f2bfu(t[ck * 4 + 0][r2]) | ((unsigned)f2bfu(t[ck * 4 + 1][r2]) << 16);
        p.y = (unsigned)f2bfu(t[ck * 4 + 2][r2]) | ((unsigned)f2bfu(t[ck * 4 + 3][r2]) << 16);
        *(uint2*)&Wt[(size_t)(bn + r2) * 512 + bk + ck * 4] = p;
    } else if (bx < 4352) {
        const int i = (bx - 2304) * 256 + threadIdx.x;
        float4 v = ((const float4*)emb)[i];
        uint2 p;
        p.x = (unsigned)f2bfu(v.x) | ((unsigned)f2bfu(v.y) << 16);
        p.y = (unsigned)f2bfu(v.z) | ((unsigned)f2bfu(v.w) << 16);
        ((uint2*)embb)[i] = p;
    } else {
        const int i = (bx - 4352) * 256 + threadIdx.x;
        const int bi = batch[i];
        if (i == 0 || batch[i - 1] != bi) {
            int e = i + 1;
            while (e < N_NODES && batch[e] == bi) ++e;
            for (int j = i; j < e; ++j) { seg_s[j] = i; seg_e[j] = e; }
        }
    }
}

// ---------------- bf16 MFMA GEMM, 128x128, BK=64, 8 waves, dbuf + counted vmcnt ----------
// Phase order (HK-style): vmcnt; barrier; ds_read all; lgkmcnt(0); barrier; STAGE; MFMA.
// MODE 0: grid.y=16, wsel=y>>2 (0: static->relu->statB bf16; 1..3: qkv->outB bf16 interleaved)
// MODE 1: grid.y=12, wsel=y>>2 (0..2: qkv->outB bf16 interleaved)
template<int MODE>
__global__ __launch_bounds__(512) void gemm128(
        const __hip_bfloat16* __restrict__ A,
        const __hip_bfloat16* __restrict__ Wt0, const __hip_bfloat16* __restrict__ Wt1,
        const __hip_bfloat16* __restrict__ Wt2, const __hip_bfloat16* __restrict__ Wt3,
        const float* __restrict__ bias0, const float* __restrict__ bias1,
        const float* __restrict__ bias2, const float* __restrict__ bias3,
        __hip_bfloat16* __restrict__ statB, __hip_bfloat16* __restrict__ outB) {
    __shared__ alignas(16) short Al[2][128][64];   // 32 KB
    __shared__ alignas(16) short Bl[2][128][64];   // 32 KB

    const int tid = threadIdx.x;
    const int wid = tid >> 6, lane = tid & 63;       // wid in [0,8)
    const int brow = blockIdx.x * 128;
    const int wsel = blockIdx.y >> 2;
    const int bcol = (blockIdx.y & 3) * 128;
    const __hip_bfloat16* Wt = (wsel == 0) ? Wt0 : (wsel == 1) ? Wt1 : (wsel == 2) ? Wt2 : Wt3;
    const float* bias        = (wsel == 0) ? bias0 : (wsel == 1) ? bias1 : (wsel == 2) ? bias2 : bias3;

    const int swzc = (lane & 7) ^ ((lane >> 3) & 7);
    const __hip_bfloat16* aSrc = A  + (size_t)(brow + wid * 16 + (lane >> 3)) * KDIM + swzc * 8;
    const __hip_bfloat16* bSrc = Wt + (size_t)(bcol + wid * 16 + (lane >> 3)) * KDIM + swzc * 8;

    const int fr = lane & 15, fq = lane >> 4;
    const int rx = fr & 7;
    const int wm = (wid >> 1) * 32;
    const int wn = (wid & 1) * 64;

    auto STAGE = [&](int buf, int t) {
        const int k0 = t * 64;
        gload_lds16(aSrc + k0, &Al[buf][wid * 16][0]);
        gload_lds16(aSrc + k0 + (size_t)8 * KDIM, &Al[buf][wid * 16 + 8][0]);
        gload_lds16(bSrc + k0, &Bl[buf][wid * 16][0]);
        gload_lds16(bSrc + k0 + (size_t)8 * KDIM, &Bl[buf][wid * 16 + 8][0]);
    };

    STAGE(0, 0);
    STAGE(1, 1);

    const int ch0 = ((0 + fq) ^ rx) * 8;
    const int ch1 = ((4 + fq) ^ rx) * 8;

    f32x4 acc[2][4] = {};
    #pragma unroll
    for (int t = 0; t < 8; ++t) {
        const int cur = t & 1;
        if (t < 7) asm volatile("s_waitcnt vmcnt(4)" ::: "memory");   // tile t staged; t+1 in flight
        else       asm volatile("s_waitcnt vmcnt(0)" ::: "memory");
        __builtin_amdgcn_s_barrier();
        __builtin_amdgcn_sched_barrier(0);
        bf16x8 a0[2], a1[2], b0[4], b1[4];
        #pragma unroll
        for (int mi = 0; mi < 2; ++mi) {
            a0[mi] = *(const bf16x8*)&Al[cur][wm + mi * 16 + fr][ch0];
            a1[mi] = *(const bf16x8*)&Al[cur][wm + mi * 16 + fr][ch1];
        }
        #pragma unroll
        for (int ni = 0; ni < 4; ++ni) {
            b0[ni] = *(const bf16x8*)&Bl[cur][wn + ni * 16 + fr][ch0];
            b1[ni] = *(const bf16x8*)&Bl[cur][wn + ni * 16 + fr][ch1];
        }
        asm volatile("s_waitcnt lgkmcnt(0)" ::: "memory");   // all my LDS reads retired
        __builtin_amdgcn_sched_barrier(0);
        __builtin_amdgcn_s_barrier();                        // all waves done reading buf[cur]
        if (t + 2 < 8) STAGE(cur, t + 2);                    // overwrite freed buffer early
        __builtin_amdgcn_sched_barrier(0);
        __builtin_amdgcn_s_setprio(1);
        #pragma unroll
        for (int mi = 0; mi < 2; ++mi)
            #pragma unroll
            for (int ni = 0; ni < 4; ++ni) {
                acc[mi][ni] = __builtin_amdgcn_mfma_f32_16x16x32_bf16(a0[mi], b0[ni], acc[mi][ni], 0, 0, 0);
                acc[mi][ni] = __builtin_amdgcn_mfma_f32_16x16x32_bf16(a1[mi], b1[ni], acc[mi][ni], 0, 0, 0);
            }
        __builtin_amdgcn_s_setprio(0);
    }

    float bv[4];
    #pragma unroll
    for (int ni = 0; ni < 4; ++ni) bv[ni] = bias[bcol + wn + ni * 16 + fr];

    #pragma unroll
    for (int mi = 0; mi < 2; ++mi) {
        #pragma unroll
        for (int ni = 0; ni < 4; ++ni) {
            const int c = bcol + wn + ni * 16 + fr;
            #pragma unroll
            for (int r = 0; r < 4; ++r) {
                const int row = brow + wm + mi * 16 + fq * 4 + r;
                const float v = acc[mi][ni][r] + bv[ni];
                if (MODE == 0) {
                    if (wsel == 0) statB[(size_t)row * 512 + c] = __float2bfloat16(fmaxf(v, 0.f));
                    else           outB[(size_t)row * 1536 + (wsel - 1) * 512 + c] = __float2bfloat16(v);
                } else {
                    outB[(size_t)row * 1536 + wsel * 512 + c] = __float2bfloat16(v);
                }
            }
        }
    }
}

// ---------------- O-projection GEMM, 64x64, BK=64, dbuf + counted vmcnt, HK phase order ------
// out = bf16( beta*(A@Wt+b) + X ), X bf16 residual; single bf16 output.
__global__ __launch_bounds__(256) void gemm_oproj(
        const __hip_bfloat16* __restrict__ A, const __hip_bfloat16* __restrict__ Wt,
        const float* __restrict__ bias,
        const __hip_bfloat16* __restrict__ X, const float* __restrict__ betaP,
        __hip_bfloat16* __restrict__ outB) {
    __shared__ alignas(16) short Al[2][64][64];   // 16 KB
    __shared__ alignas(16) short Bl[2][64][64];   // 16 KB

    const int tid = threadIdx.x;
    const int wid = tid >> 6, lane = tid & 63;   // wid in [0,4)
    const int brow = blockIdx.x * 64;
    const int bcol = blockIdx.y * 64;

    const int swzc = (lane & 7) ^ ((lane >> 3) & 7);
    const __hip_bfloat16* aSrc = A  + (size_t)(brow + wid * 16 + (lane >> 3)) * KDIM + swzc * 8;
    const __hip_bfloat16* bSrc = Wt + (size_t)(bcol + wid * 16 + (lane >> 3)) * KDIM + swzc * 8;

    const int fr = lane & 15, fq = lane >> 4;
    const int rx = fr & 7;
    const int wm = (wid >> 1) * 32, wn = (wid & 1) * 32;

    auto STAGE = [&](int buf, int t) {
        const int k0 = t * 64;
        gload_lds16(aSrc + k0, &Al[buf][wid * 16][0]);
        gload_lds16(aSrc + k0 + (size_t)8 * KDIM, &Al[buf][wid * 16 + 8][0]);
        gload_lds16(bSrc + k0, &Bl[buf][wid * 16][0]);
        gload_lds16(bSrc + k0 + (size_t)8 * KDIM, &Bl[buf][wid * 16 + 8][0]);
    };

    STAGE(0, 0);
    STAGE(1, 1);

    const int ch0 = ((0 + fq) ^ rx) * 8;
    const int ch1 = ((4 + fq) ^ rx) * 8;

    f32x4 acc[2][2] = {};
    #pragma unroll
    for (int t = 0; t < 8; ++t) {
        const int cur = t & 1;
        if (t < 7) asm volatile("s_waitcnt vmcnt(4)" ::: "memory");
        else       asm volatile("s_waitcnt vmcnt(0)" ::: "memory");
        __builtin_amdgcn_s_barrier();
        __builtin_amdgcn_sched_barrier(0);
        bf16x8 a0[2], a1[2], b0[2], b1[2];
        #pragma unroll
        for (int mi = 0; mi < 2; ++mi) {
            a0[mi] = *(const bf16x8*)&Al[cur][wm + mi * 16 + fr][ch0];
            a1[mi] = *(const bf16x8*)&Al[cur][wm + mi * 16 + fr][ch1];
        }
        #pragma unroll
        for (int ni = 0; ni < 2; ++ni) {
            b0[ni] = *(const bf16x8*)&Bl[cur][wn + ni * 16 + fr][ch0];
            b1[ni] = *(const bf16x8*)&Bl[cur][wn + ni * 16 + fr][ch1];
        }
        asm volatile("s_waitcnt lgkmcnt(0)" ::: "memory");
        __builtin_amdgcn_sched_barrier(0);
        __builtin_amdgcn_s_barrier();
        if (t + 2 < 8) STAGE(cur, t + 2);
        __builtin_amdgcn_sched_barrier(0);
        __builtin_amdgcn_s_setprio(1);
        #pragma unroll
        for (int mi = 0; mi < 2; ++mi)
            #pragma unroll
            for (int ni = 0; ni < 2; ++ni) {
                acc[mi][ni] = __builtin_amdgcn_mfma_f32_16x16x32_bf16(a0[mi], b0[ni], acc[mi][ni], 0, 0, 0);
                acc[mi][ni] = __builtin_amdgcn_mfma_f32_16x16x32_bf16(a1[mi], b1[ni], acc[mi][ni], 0, 0, 0);
            }
        __builtin_amdgcn_s_setprio(0);
    }

    float bv[2];
    #pragma unroll
    for (int ni = 0; ni < 2; ++ni) bv[ni] = bias[bcol + wn + ni * 16 + fr];
    const float beta = betaP[0];

    #pragma unroll
    for (int mi = 0; mi < 2; ++mi) {
        #pragma unroll
        for (int ni = 0; ni < 2; ++ni) {
            const int c = bcol + wn + ni * 16 + fr;
            #pragma unroll
            for (int r = 0; r < 4; ++r) {
                const int row = brow + wm + mi * 16 + fq * 4 + r;
                const float xv = __bfloat162float(X[(size_t)row * 512 + c]);
                outB[(size_t)row * 512 + c] =
                    __float2bfloat16(beta * (acc[mi][ni][r] + bv[ni]) + xv);
            }
        }
    }
}

// ---------------- masked segment attention: one wave per NODE, 512-thr blocks ----------------
__global__ __launch_bounds__(512) void attn_kernel(
        const __hip_bfloat16* __restrict__ qkv,
        const int* __restrict__ seg_s, const int* __restrict__ seg_e,
        __hip_bfloat16* __restrict__ ab) {
    const int node = (int)(blockIdx.x * blockDim.x + threadIdx.x) >> 6;
    const int lane = threadIdx.x & 63;
    const int c8   = lane * 8;

    bf16x8 q8 = *(const bf16x8*)&qkv[(size_t)node * 1536 + c8];
    float qf[8];
    #pragma unroll
    for (int j = 0; j < 8; ++j) qf[j] = bfu2f((unsigned short)q8[j]);

    const int s = seg_s[node], e = seg_e[node];

    float M = -INFINITY, S = 0.f;
    float o[8] = {};
    for (int m = s; m < e; ++m) {
        if (m == node) continue;
        bf16x8 k8 = *(const bf16x8*)&qkv[(size_t)m * 1536 + 512 + c8];
        float p = 0.f;
        #pragma unroll
        for (int j = 0; j < 8; ++j) p = fmaf(qf[j], bfu2f((unsigned short)k8[j]), p);
        p += __shfl_xor(p, 1, 64);
        p += __shfl_xor(p, 2, 64);
        p += __shfl_xor(p, 4, 64);
        const float sc = p * 0.125f;
        const float newM = fmaxf(M, sc);
        const float scale = __expf(M - newM);
        const float w = __expf(sc - newM);
        S = S * scale + w;
        bf16x8 v8 = *(const bf16x8*)&qkv[(size_t)m * 1536 + 1024 + c8];
        #pragma unroll
        for (int j = 0; j < 8; ++j) o[j] = fmaf(w, bfu2f((unsigned short)v8[j]), o[j] * scale);
        M = newM;
    }
    const float inv = (S > 0.f) ? (1.f / S) : 0.f;
    bf16x8 r;
    #pragma unroll
    for (int j = 0; j < 8; ++j) r[j] = (short)f2bfu(o[j] * inv);
    *(bf16x8*)&ab[(size_t)node * 512 + c8] = r;
}

// ---------------- per-set mean of squared diff (bf16 inputs, fp32 accumulate/output) --------
__global__ __launch_bounds__(256) void seg_mse_kernel(
        const unsigned short* __restrict__ dyn, const unsigned short* __restrict__ stat,
        const int* __restrict__ batch, float* __restrict__ out) {
    const int s = blockIdx.x;
    const int d = threadIdx.x * 2;
    int lo = 0, hi = N_NODES;
    while (lo < hi) { int m = (lo + hi) >> 1; if (batch[m] < s) lo = m + 1; else hi = m; }
    const int a = lo;
    hi = N_NODES;
    while (lo < hi) { int m = (lo + hi) >> 1; if (batch[m] <= s) lo = m + 1; else hi = m; }
    const int b = lo;

    float acc0 = 0.f, acc1 = 0.f;
    for (int i = a; i < b; ++i) {
        const unsigned dv = *(const unsigned*)&dyn[(size_t)i * 512 + d];
        const unsigned sv = *(const unsigned*)&stat[(size_t)i * 512 + d];
        const float d0 = bfu2f((unsigned short)(dv & 0xffff)) - bfu2f((unsigned short)(sv & 0xffff));
        const float d1 = bfu2f((unsigned short)(dv >> 16))   - bfu2f((unsigned short)(sv >> 16));
        acc0 += d0 * d0; acc1 += d1 * d1;
    }
    const float inv = 1.f / fmaxf((float)(b - a), 1.f);
    float2 r; r.x = acc0 * inv; r.y = acc1 * inv;
    *(float2*)&out[(size_t)s * 512 + d] = r;
}

extern "C" void kernel_launch(void* const* d_in, const int* in_sizes, int n_in,
                              void* d_out, int out_size, void* d_ws, size_t ws_size,
                              hipStream_t stream) {
    const float* emb   = (const float*)d_in[0];
    const int*   batch = (const int*)  d_in[1];
    const float* Ws_   = (const float*)d_in[2];
    const float* bs_   = (const float*)d_in[3];
    const float* Wq1 = (const float*)d_in[4];  const float* bq1 = (const float*)d_in[5];
    const float* Wk1 = (const float*)d_in[6];  const float* bk1 = (const float*)d_in[7];
    const float* Wv1 = (const float*)d_in[8];  const float* bv1 = (const float*)d_in[9];
    const float* Wo1 = (const float*)d_in[10]; const float* bo1 = (const float*)d_in[11];
    const float* beta1 = (const float*)d_in[12];
    const float* Wq2 = (const float*)d_in[13]; const float* bq2 = (const float*)d_in[14];
    const float* Wk2 = (const float*)d_in[15]; const float* bk2 = (const float*)d_in[16];
    const float* Wv2 = (const float*)d_in[17]; const float* bv2 = (const float*)d_in[18];
    const float* Wo2 = (const float*)d_in[19]; const float* bo2 = (const float*)d_in[20];
    const float* beta2 = (const float*)d_in[21];

    char* w = (char*)d_ws;
    const size_t MB = 1024 * 1024;
    __hip_bfloat16* statB  = (__hip_bfloat16*)(w + 0 * MB);   // 4 MiB
    __hip_bfloat16* qkv    = (__hip_bfloat16*)(w + 4 * MB);   // 12 MiB
    __hip_bfloat16* embb   = (__hip_bfloat16*)(w + 16 * MB);  // 4 MiB
    __hip_bfloat16* ab     = (__hip_bfloat16*)(w + 20 * MB);  // 4 MiB
    __hip_bfloat16* dynb   = (__hip_bfloat16*)(w + 24 * MB);  // 4 MiB (layer-1 output)
    __hip_bfloat16* dyn2b  = (__hip_bfloat16*)(w + 28 * MB);  // 4 MiB (layer-2 output)
    __hip_bfloat16* wt     = (__hip_bfloat16*)(w + 32 * MB);  // 4.5 MiB (9 x 512x512)
    int* seg_s = (int*)(w + 37 * MB);
    int* seg_e = seg_s + N_NODES;

    const size_t WSZ = 512 * 512;
    __hip_bfloat16* wtS  = wt + 0 * WSZ;
    __hip_bfloat16* wtQ1 = wt + 1 * WSZ;
    __hip_bfloat16* wtK1 = wt + 2 * WSZ;
    __hip_bfloat16* wtV1 = wt + 3 * WSZ;
    __hip_bfloat16* wtO1 = wt + 4 * WSZ;
    __hip_bfloat16* wtQ2 = wt + 5 * WSZ;
    __hip_bfloat16* wtK2 = wt + 6 * WSZ;
    __hip_bfloat16* wtV2 = wt + 7 * WSZ;
    __hip_bfloat16* wtO2 = wt + 8 * WSZ;

    prep_kernel<<<4368, 256, 0, stream>>>(
        Ws_, Wq1, Wk1, Wv1, Wo1, Wq2, Wk2, Wv2, Wo2, wt,
        emb, embb, batch, seg_s, seg_e);

    // layer 1: fused static + QKV
    gemm128<0><<<dim3(32, 16), 512, 0, stream>>>(
        embb, wtS, wtQ1, wtK1, wtV1, bs_, bq1, bk1, bv1, statB, qkv);
    attn_kernel<<<N_NODES / 8, 512, 0, stream>>>(qkv, seg_s, seg_e, ab);
    gemm_oproj<<<dim3(64, 8), 256, 0, stream>>>(ab, wtO1, bo1, embb, beta1, dynb);

    // layer 2: fused QKV
    gemm128<1><<<dim3(32, 12), 512, 0, stream>>>(
        dynb, wtQ2, wtK2, wtV2, wtV2, bq2, bk2, bv2, bv2, nullptr, qkv);
    attn_kernel<<<N_NODES / 8, 512, 0, stream>>>(qkv, seg_s, seg_e, ab);
    gemm_oproj<<<dim3(64, 8), 256, 0, stream>>>(ab, wtO2, bo2, dynb, beta2, dyn2b);

    seg_mse_kernel<<<NUM_SETS, 256, 0, stream>>>(
        (const unsigned short*)dyn2b, (const unsigned short*)statB, batch, (float*)d_out);
}